// Round 13
// baseline (288.860 us; speedup 1.0000x reference)
//
#include <hip/hip_runtime.h>

// GIN fused: msg = node_feat[src] + edge_feat; agg = segment_sum(msg, dst);
// out = relu(agg@w1+b1)@w2+b2.  N=50000, E=800000, H=128.
//
// Round 13: gather fused into the MFMA MLP kernel. One block = 64 nodes:
// phase 1 gathers 16 rows/wave -> bf16 LDS tile (stride 136 shorts, <=2-way
// banks); phase 2 = verified MFMA MLP reading A-frags from LDS. Kills the
// 25.6MB aggb round-trip + a launch gap, and lets memory-phase blocks
// co-schedule with MFMA-phase blocks on the same CU.

constexpr int NN  = 50000;
constexpr int NE  = 800000;
constexpr int H   = 128;   // hidden
constexpr int H2  = 256;   // 2*hidden
constexpr int SHP = 264;   // bf16 LDS row stride (h tile)
constexpr int SIN = 136;   // bf16 LDS row stride (input tile; 272B -> 2-way max)
constexpr int CAP = 64;    // bucket capacity per node

typedef short short8_t __attribute__((ext_vector_type(8)));
typedef float f32x4    __attribute__((ext_vector_type(4)));
typedef int   i32x4    __attribute__((ext_vector_type(4)));

__device__ inline short f2bf(float f) {
    union { float f; unsigned u; } c; c.f = f;
    unsigned r = c.u + 0x7FFF + ((c.u >> 16) & 1);   // RTNE
    return (short)(r >> 16);
}

__device__ inline f32x4 nt4(const float* p) {
    return __builtin_nontemporal_load((const f32x4*)p);
}

// ---------------------------------------------------------------------------
// Weight pack (MFMA B-fragment layout, verified round 8) + cursor zeroing.
// ---------------------------------------------------------------------------
__global__ __launch_bounds__(256) void pack_zero_kernel(
    const float* __restrict__ w1, const float* __restrict__ w2,
    short* __restrict__ w1p, short* __restrict__ w2p,
    int* __restrict__ cursor)
{
    int i = blockIdx.x * 256 + threadIdx.x;   // 0..32767
    {
        int j = i & 7, l = (i >> 3) & 63, ct = (i >> 9) & 15, kk = i >> 13;
        w1p[i] = f2bf(w1[(kk * 32 + (l >> 4) * 8 + j) * H2 + ct * 16 + (l & 15)]);
    }
    {
        int j = i & 7, l = (i >> 3) & 63, ct = (i >> 9) & 7, kk = i >> 12;
        w2p[i] = f2bf(w2[(kk * 32 + (l >> 4) * 8 + j) * H + ct * 16 + (l & 15)]);
    }
    if (i < NN) cursor[i] = 0;
    const int i2 = i + 32768;
    if (i2 < NN) cursor[i2] = 0;
}

// ---------------------------------------------------------------------------
// Place: 2 edges per thread (int2 loads), append (eid, src) to dst bucket.
// ---------------------------------------------------------------------------
__global__ __launch_bounds__(256) void place_kernel(
    const int* __restrict__ edge_dst, const int* __restrict__ edge_src,
    int* __restrict__ cursor, int2* __restrict__ bucket)
{
    const int e0 = (blockIdx.x * blockDim.x + threadIdx.x) * 2;
    if (e0 + 1 < NE) {
        const int2 d = *(const int2*)&edge_dst[e0];
        const int2 s = *(const int2*)&edge_src[e0];
        const int p0 = atomicAdd(&cursor[d.x], 1);
        bucket[(size_t)d.x * CAP + p0] = make_int2(e0, s.x);
        const int p1 = atomicAdd(&cursor[d.y], 1);
        bucket[(size_t)d.y * CAP + p1] = make_int2(e0 + 1, s.y);
    } else if (e0 < NE) {
        const int d = edge_dst[e0];
        const int s = edge_src[e0];
        const int p = atomicAdd(&cursor[d], 1);
        bucket[(size_t)d * CAP + p] = make_int2(e0, s);
    }
}

// ---------------------------------------------------------------------------
// Fused gather + MLP. Block = 256 threads = 4 waves = 64 nodes.
// Phase 1: wave w gathers rows w*16..w*16+15 (half-wave f32x4 scheme,
//   verified rounds 10-12) -> bf16 into s_in[64][SIN].
// Phase 2: MFMA MLP (verified rounds 8-12), A-frags from s_in.
// ---------------------------------------------------------------------------
__global__ __launch_bounds__(256) void fused_kernel(
    const float* __restrict__ node_feat,
    const float* __restrict__ edge_feat,
    const int2*  __restrict__ bucket,
    const int*   __restrict__ cursor,
    const short* __restrict__ w1p, const short* __restrict__ w2p,
    const float* __restrict__ b1,  const float* __restrict__ b2,
    float*       __restrict__ out)
{
    __shared__ short s_in[64 * SIN];            // 17,408 B
    __shared__ short smem[4 * 16 * SHP];        // 33,792 B  (total 51,200)

    const int t = threadIdx.x;
    const int wid = t >> 6, l = t & 63;
    const int h   = l >> 5;                     // half-wave id
    const int c4  = (l & 31) * 4;               // float column
    const long long nbase = (long long)blockIdx.x * 64;

    // ---- phase 1: gather ----
    for (int nl = 0; nl < 16; ++nl) {
        const int lrow_n = wid * 16 + nl;       // local row 0..63
        const long long node = nbase + lrow_n;
        const int deg = (node < NN) ? cursor[node] : 0;
        const int2* bk = bucket + (size_t)node * CAP;
        f32x4 acc = {0.f, 0.f, 0.f, 0.f};
        int i = 0;
        const int ng = deg >> 2;
        i32x4 c0 = {0, 0, 0, 0}, c1 = {0, 0, 0, 0};
        if (ng > 0) {
            c0 = *(const i32x4*)&bk[0];
            c1 = *(const i32x4*)&bk[2];
        }
        for (int g = 0; g < ng; ++g) {
            const i32x4 q0 = c0, q1 = c1;
            if (g + 1 < ng) {                   // cached index prefetch
                c0 = *(const i32x4*)&bk[i + 4];
                c1 = *(const i32x4*)&bk[i + 6];
            }
            const int e0 = h ? q0.z : q0.x, s0 = h ? q0.w : q0.y;
            const int e1 = h ? q1.z : q1.x, s1 = h ? q1.w : q1.y;
            const f32x4 a0 = nt4(edge_feat + (size_t)e0 * H + c4);
            const f32x4 b0 = *(const f32x4*)(node_feat + (size_t)s0 * H + c4);
            const f32x4 a1 = nt4(edge_feat + (size_t)e1 * H + c4);
            const f32x4 b1v = *(const f32x4*)(node_feat + (size_t)s1 * H + c4);
            acc += a0 + b0;
            acc += a1 + b1v;
            i += 4;
        }
        if (i + 2 <= deg) {                     // 2-edge group
            const i32x4 p0 = *(const i32x4*)&bk[i];
            const int e0 = h ? p0.z : p0.x, s0 = h ? p0.w : p0.y;
            const f32x4 a0 = nt4(edge_feat + (size_t)e0 * H + c4);
            const f32x4 b0 = *(const f32x4*)(node_feat + (size_t)s0 * H + c4);
            acc += a0 + b0;
            i += 2;
        }
        if (i < deg && h == 0) {                // single tail edge
            const int2 es = bk[i];
            const f32x4 ef = nt4(edge_feat + (size_t)es.x * H + c4);
            const f32x4 nf = *(const f32x4*)(node_feat + (size_t)es.y * H + c4);
            acc += ef + nf;
        }
        acc.x += __shfl_xor(acc.x, 32);
        acc.y += __shfl_xor(acc.y, 32);
        acc.z += __shfl_xor(acc.z, 32);
        acc.w += __shfl_xor(acc.w, 32);
        if (h == 0) {
            const unsigned lo = (unsigned)(unsigned short)f2bf(acc.x)
                              | ((unsigned)(unsigned short)f2bf(acc.y) << 16);
            const unsigned hi = (unsigned)(unsigned short)f2bf(acc.z)
                              | ((unsigned)(unsigned short)f2bf(acc.w) << 16);
            *(uint2*)&s_in[lrow_n * SIN + c4] = make_uint2(lo, hi);
        }
    }
    __syncthreads();

    // ---- phase 2: MLP ----
    const int lrow = l & 15, lk = l >> 4;
    const long long mrow = nbase + wid * 16;
    short* s_h = &smem[wid * 16 * SHP];

    // layer 1
    f32x4 acc[16];
    #pragma unroll
    for (int ct = 0; ct < 16; ++ct) acc[ct] = (f32x4){0.f, 0.f, 0.f, 0.f};
    const short8_t* bfr1 = (const short8_t*)w1p;
    #pragma unroll
    for (int kk = 0; kk < 4; ++kk) {
        const short8_t a =
            *(const short8_t*)&s_in[(wid * 16 + lrow) * SIN + kk * 32 + lk * 8];
        #pragma unroll
        for (int ct = 0; ct < 16; ++ct)
            acc[ct] = __builtin_amdgcn_mfma_f32_16x16x32_bf16(
                a, bfr1[(kk * 16 + ct) * 64 + l], acc[ct], 0, 0, 0);
    }
    #pragma unroll
    for (int ct = 0; ct < 16; ++ct) {
        const float b = b1[ct * 16 + lrow];
        #pragma unroll
        for (int r = 0; r < 4; ++r) {
            float v = acc[ct][r] + b;
            s_h[(lk * 4 + r) * SHP + ct * 16 + lrow] = f2bf(v > 0.f ? v : 0.f);
        }
    }
    __syncthreads();

    // layer 2
    f32x4 acc2[8];
    #pragma unroll
    for (int ct = 0; ct < 8; ++ct) acc2[ct] = (f32x4){0.f, 0.f, 0.f, 0.f};
    const short8_t* bfr2 = (const short8_t*)w2p;
    #pragma unroll
    for (int kk = 0; kk < 8; ++kk) {
        const short8_t a = *(const short8_t*)&s_h[lrow * SHP + kk * 32 + lk * 8];
        #pragma unroll
        for (int ct = 0; ct < 8; ++ct)
            acc2[ct] = __builtin_amdgcn_mfma_f32_16x16x32_bf16(
                a, bfr2[(kk * 8 + ct) * 64 + l], acc2[ct], 0, 0, 0);
    }
    __syncthreads();

    float* sc = (float*)s_h;
    #pragma unroll
    for (int ct = 0; ct < 8; ++ct) {
        const float b = b2[ct * 16 + lrow];
        #pragma unroll
        for (int r = 0; r < 4; ++r)
            sc[(lk * 4 + r) * 132 + ct * 16 + lrow] = acc2[ct][r] + b;
    }
    __syncthreads();

    #pragma unroll
    for (int it = 0; it < 8; ++it) {
        const int off = it * 64 + l;            // float4 units, 0..511
        const long long row = mrow + (off >> 5);
        if (row < NN) {
            const float4 v = *(const float4*)&sc[(off >> 5) * 132 + (off & 31) * 4];
            *(float4*)(out + row * H + (off & 31) * 4) = v;
        }
    }
}

// ---------------------------------------------------------------------------
// Fallback path (tiny workspace): atomic scatter + simple MLP (all fp32).
// ---------------------------------------------------------------------------
__global__ __launch_bounds__(256) void scatter_kernel(
    const float* __restrict__ node_feat,
    const float* __restrict__ edge_feat,
    const int*   __restrict__ edge_src,
    const int*   __restrict__ edge_dst,
    float*       __restrict__ agg)
{
    long long tid = (long long)blockIdx.x * blockDim.x + threadIdx.x;
    const long long total = (long long)NE * 32;
    if (tid >= total) return;
    int e = (int)(tid >> 5);
    int q = (int)((tid & 31) << 2);
    int s = edge_src[e];
    int d = edge_dst[e];
    const float4 nf = *(const float4*)(node_feat + (long long)s * H + q);
    const float4 ef = *(const float4*)(edge_feat + (long long)e * H + q);
    float* dst = agg + (long long)d * H + q;
    atomicAdd(dst + 0, nf.x + ef.x);
    atomicAdd(dst + 1, nf.y + ef.y);
    atomicAdd(dst + 2, nf.z + ef.z);
    atomicAdd(dst + 3, nf.w + ef.w);
}

__global__ __launch_bounds__(256) void mlp_simple_kernel(
    const float* __restrict__ agg,
    const float* __restrict__ w1, const float* __restrict__ b1,
    const float* __restrict__ w2, const float* __restrict__ b2,
    float*       __restrict__ out)
{
    constexpr int NPB = 16;
    __shared__ float s_in[NPB][H];
    __shared__ float s_h [NPB][H2];
    const int t = threadIdx.x;
    const long long base = (long long)blockIdx.x * NPB;
    {
        const float4* src = (const float4*)(agg + base * H);
        float4* dst = (float4*)(&s_in[0][0]);
        dst[t]       = src[t];
        dst[t + 256] = src[t + 256];
    }
    __syncthreads();
    float acc[NPB];
    {
        const float b = b1[t];
        #pragma unroll
        for (int n = 0; n < NPB; ++n) acc[n] = b;
    }
    #pragma unroll 4
    for (int k = 0; k < H; ++k) {
        const float w = w1[k * H2 + t];
        #pragma unroll
        for (int n = 0; n < NPB; ++n) acc[n] = fmaf(s_in[n][k], w, acc[n]);
    }
    #pragma unroll
    for (int n = 0; n < NPB; ++n) s_h[n][t] = fmaxf(acc[n], 0.0f);
    __syncthreads();
    const int j = t & (H - 1);
    const int g = t >> 7;
    float acc2[NPB / 2];
    {
        const float b = b2[j];
        #pragma unroll
        for (int n = 0; n < NPB / 2; ++n) acc2[n] = b;
    }
    #pragma unroll 4
    for (int k = 0; k < H2; ++k) {
        const float w = w2[k * H + j];
        #pragma unroll
        for (int n = 0; n < NPB / 2; ++n)
            acc2[n] = fmaf(s_h[g * (NPB / 2) + n][k], w, acc2[n]);
    }
    #pragma unroll
    for (int n = 0; n < NPB / 2; ++n)
        out[(base + g * (NPB / 2) + n) * H + j] = acc2[n];
}

__global__ __launch_bounds__(256) void zero_agg_kernel(float4* __restrict__ p, int n4)
{
    int i = blockIdx.x * blockDim.x + threadIdx.x;
    if (i < n4) p[i] = make_float4(0.f, 0.f, 0.f, 0.f);
}

// ---------------------------------------------------------------------------
extern "C" void kernel_launch(void* const* d_in, const int* in_sizes, int n_in,
                              void* d_out, int out_size, void* d_ws, size_t ws_size,
                              hipStream_t stream)
{
    const float* node_feat = (const float*)d_in[0];
    const float* edge_feat = (const float*)d_in[1];
    const int*   edge_src  = (const int*)  d_in[2];
    const int*   edge_dst  = (const int*)  d_in[3];
    const float* w1 = (const float*)d_in[4];
    const float* b1 = (const float*)d_in[5];
    const float* w2 = (const float*)d_in[6];
    const float* b2 = (const float*)d_in[7];
    float* out = (float*)d_out;

    // Workspace layout (256-B aligned regions)
    const size_t cursor_b = ((size_t)NN * 4 + 255) & ~(size_t)255;         // 200 KB
    const size_t w1p_b    = (size_t)32768 * 2;                             // 64 KB
    const size_t w2p_b    = (size_t)32768 * 2;                             // 64 KB
    const size_t bucket_b = (size_t)NN * CAP * 8;                          // 25.6 MB
    const size_t need     = cursor_b + w1p_b + w2p_b + bucket_b;           // ~25.9 MB

    if (ws_size >= need) {
        char* p = (char*)d_ws;
        int*   cursor = (int*)p;                 p += cursor_b;
        short* w1p    = (short*)p;               p += w1p_b;
        short* w2p    = (short*)p;               p += w2p_b;
        int2*  bucket = (int2*)p;

        pack_zero_kernel<<<128, 256, 0, stream>>>(w1, w2, w1p, w2p, cursor);
        const int eb = 256;
        const int eg = (NE / 2 + eb - 1) / eb;         // 1563 (2 edges/thread)
        place_kernel<<<eg, eb, 0, stream>>>(edge_dst, edge_src, cursor, bucket);
        const int fgrid = (NN + 63) / 64;              // 782
        fused_kernel<<<fgrid, 256, 0, stream>>>(
            node_feat, edge_feat, bucket, cursor, w1p, w2p, b1, b2, out);
    } else {
        // Fallback: atomic path + simple fp32 MLP
        const size_t agg_bytes = (size_t)NN * H * sizeof(float);
        float* agg = (ws_size >= agg_bytes) ? (float*)d_ws : out;
        {
            const int n4 = (int)(agg_bytes / 16);
            zero_agg_kernel<<<(n4 + 255) / 256, 256, 0, stream>>>((float4*)agg, n4);
        }
        const long long total = (long long)NE * 32;
        const int block = 256;
        const int grid  = (int)((total + block - 1) / block);
        scatter_kernel<<<grid, block, 0, stream>>>(
            node_feat, edge_feat, edge_src, edge_dst, agg);
        mlp_simple_kernel<<<NN / 16, 256, 0, stream>>>(agg, w1, b1, w2, b2, out);
    }
}

// Round 14
// 220.689 us; speedup vs baseline: 1.3089x; 1.3089x over previous
//
#include <hip/hip_runtime.h>

// GIN fused: msg = node_feat[src] + edge_feat; agg = segment_sum(msg, dst);
// out = relu(agg@w1+b1)@w2+b2.  N=50000, E=800000, H=128.
//
// Round 14: revert to round-12 structure (fusion in r13 cost 2.5x gather
// occupancy: 51KB LDS -> 3 blocks/CU -> hbm 1.7TB/s). Only change vs r12:
// gather unrolls to 8 edges/iteration (16 loads in flight per wave).

constexpr int NN  = 50000;
constexpr int NE  = 800000;
constexpr int H   = 128;   // hidden
constexpr int H2  = 256;   // 2*hidden
constexpr int SHP = 264;   // bf16 LDS row stride
constexpr int CAP = 64;    // bucket capacity per node

typedef short short8_t __attribute__((ext_vector_type(8)));
typedef float f32x4    __attribute__((ext_vector_type(4)));
typedef int   i32x4    __attribute__((ext_vector_type(4)));

__device__ inline short f2bf(float f) {
    union { float f; unsigned u; } c; c.f = f;
    unsigned r = c.u + 0x7FFF + ((c.u >> 16) & 1);   // RTNE
    return (short)(r >> 16);
}

__device__ inline f32x4 nt4(const float* p) {
    return __builtin_nontemporal_load((const f32x4*)p);
}

// ---------------------------------------------------------------------------
// Weight pack (MFMA B-fragment layout, verified round 8) + cursor zeroing.
// ---------------------------------------------------------------------------
__global__ __launch_bounds__(256) void pack_zero_kernel(
    const float* __restrict__ w1, const float* __restrict__ w2,
    short* __restrict__ w1p, short* __restrict__ w2p,
    int* __restrict__ cursor)
{
    int i = blockIdx.x * 256 + threadIdx.x;   // 0..32767
    {
        int j = i & 7, l = (i >> 3) & 63, ct = (i >> 9) & 15, kk = i >> 13;
        w1p[i] = f2bf(w1[(kk * 32 + (l >> 4) * 8 + j) * H2 + ct * 16 + (l & 15)]);
    }
    {
        int j = i & 7, l = (i >> 3) & 63, ct = (i >> 9) & 7, kk = i >> 12;
        w2p[i] = f2bf(w2[(kk * 32 + (l >> 4) * 8 + j) * H + ct * 16 + (l & 15)]);
    }
    if (i < NN) cursor[i] = 0;
    const int i2 = i + 32768;
    if (i2 < NN) cursor[i2] = 0;
}

// ---------------------------------------------------------------------------
// Place: 2 edges per thread (int2 loads), append (eid, src) to dst bucket.
// ---------------------------------------------------------------------------
__global__ __launch_bounds__(256) void place_kernel(
    const int* __restrict__ edge_dst, const int* __restrict__ edge_src,
    int* __restrict__ cursor, int2* __restrict__ bucket)
{
    const int e0 = (blockIdx.x * blockDim.x + threadIdx.x) * 2;
    if (e0 + 1 < NE) {
        const int2 d = *(const int2*)&edge_dst[e0];
        const int2 s = *(const int2*)&edge_src[e0];
        const int p0 = atomicAdd(&cursor[d.x], 1);
        bucket[(size_t)d.x * CAP + p0] = make_int2(e0, s.x);
        const int p1 = atomicAdd(&cursor[d.y], 1);
        bucket[(size_t)d.y * CAP + p1] = make_int2(e0 + 1, s.y);
    } else if (e0 < NE) {
        const int d = edge_dst[e0];
        const int s = edge_src[e0];
        const int p = atomicAdd(&cursor[d], 1);
        bucket[(size_t)d * CAP + p] = make_int2(e0, s);
    }
}

// ---------------------------------------------------------------------------
// Gather: one 64-lane wave per node. Half-wave layout: lanes 0-31 edge i,
// lanes 32-63 edge i+1, f32x4 per lane -> 1 feature-load instr per edge row.
// 8-edge main loop (16 feature loads in flight), cached index prefetch.
// nt only on edge_feat (read-once stream).
// ---------------------------------------------------------------------------
__global__ __launch_bounds__(256) void gather_kernel(
    const float* __restrict__ node_feat,
    const float* __restrict__ edge_feat,
    const int2*  __restrict__ bucket,
    const int*   __restrict__ cursor,
    short*       __restrict__ aggb)
{
    const int node = blockIdx.x * 4 + (threadIdx.x >> 6);
    const int lane = threadIdx.x & 63;
    const int h    = lane >> 5;                 // half-wave id
    const int c4   = (lane & 31) * 4;           // float column
    const int deg  = cursor[node];
    const int2* bk = bucket + (size_t)node * CAP;
    f32x4 acc = {0.f, 0.f, 0.f, 0.f};
    int i = 0;

    // main loop: 8 edges per iteration, indices loaded up-front
    for (; i + 8 <= deg; i += 8) {
        const i32x4 q0 = *(const i32x4*)&bk[i];
        const i32x4 q1 = *(const i32x4*)&bk[i + 2];
        const i32x4 q2 = *(const i32x4*)&bk[i + 4];
        const i32x4 q3 = *(const i32x4*)&bk[i + 6];
        const int e0 = h ? q0.z : q0.x, s0 = h ? q0.w : q0.y;
        const int e1 = h ? q1.z : q1.x, s1 = h ? q1.w : q1.y;
        const int e2 = h ? q2.z : q2.x, s2 = h ? q2.w : q2.y;
        const int e3 = h ? q3.z : q3.x, s3 = h ? q3.w : q3.y;
        const f32x4 a0 = nt4(edge_feat + (size_t)e0 * H + c4);
        const f32x4 b0 = *(const f32x4*)(node_feat + (size_t)s0 * H + c4);
        const f32x4 a1 = nt4(edge_feat + (size_t)e1 * H + c4);
        const f32x4 b1 = *(const f32x4*)(node_feat + (size_t)s1 * H + c4);
        const f32x4 a2 = nt4(edge_feat + (size_t)e2 * H + c4);
        const f32x4 b2 = *(const f32x4*)(node_feat + (size_t)s2 * H + c4);
        const f32x4 a3 = nt4(edge_feat + (size_t)e3 * H + c4);
        const f32x4 b3 = *(const f32x4*)(node_feat + (size_t)s3 * H + c4);
        acc += a0 + b0;
        acc += a1 + b1;
        acc += a2 + b2;
        acc += a3 + b3;
    }
    for (; i + 2 <= deg; i += 2) {              // 2-edge groups
        const i32x4 p0 = *(const i32x4*)&bk[i];
        const int e0 = h ? p0.z : p0.x, s0 = h ? p0.w : p0.y;
        const f32x4 a0 = nt4(edge_feat + (size_t)e0 * H + c4);
        const f32x4 b0 = *(const f32x4*)(node_feat + (size_t)s0 * H + c4);
        acc += a0 + b0;
    }
    if (i < deg && h == 0) {                    // single tail edge
        const int2 es = bk[i];
        const f32x4 ef = nt4(edge_feat + (size_t)es.x * H + c4);
        const f32x4 nf = *(const f32x4*)(node_feat + (size_t)es.y * H + c4);
        acc += ef + nf;
    }

    acc.x += __shfl_xor(acc.x, 32);
    acc.y += __shfl_xor(acc.y, 32);
    acc.z += __shfl_xor(acc.z, 32);
    acc.w += __shfl_xor(acc.w, 32);

    if (h == 0) {
        const unsigned lo = (unsigned)(unsigned short)f2bf(acc.x)
                          | ((unsigned)(unsigned short)f2bf(acc.y) << 16);
        const unsigned hi = (unsigned)(unsigned short)f2bf(acc.z)
                          | ((unsigned)(unsigned short)f2bf(acc.w) << 16);
        *(uint2*)(aggb + (size_t)node * H + c4) = make_uint2(lo, hi);
    }
}

// ---------------------------------------------------------------------------
// Fused MLP (rounds 9-12, verified): out = relu(agg@w1+b1)@w2+b2, bf16 MFMA.
// ---------------------------------------------------------------------------
__global__ __launch_bounds__(256) void mlp_kernel(
    const short* __restrict__ aggb, const short* __restrict__ w1p,
    const short* __restrict__ w2p,  const float* __restrict__ b1,
    const float* __restrict__ b2,   float* __restrict__ out)
{
    __shared__ short smem[4 * 16 * SHP];        // 33,792 B
    const int t = threadIdx.x;
    const int wid = t >> 6, l = t & 63;
    const int lrow = l & 15, lk = l >> 4;
    const long long mrow = (long long)blockIdx.x * 64 + wid * 16;
    short* s_h = &smem[wid * 16 * SHP];

    // ---- layer 1 ----
    f32x4 acc[16];
    #pragma unroll
    for (int ct = 0; ct < 16; ++ct) acc[ct] = (f32x4){0.f, 0.f, 0.f, 0.f};
    const short8_t* bfr1 = (const short8_t*)w1p;
    #pragma unroll
    for (int kk = 0; kk < 4; ++kk) {
        short8_t a = {0, 0, 0, 0, 0, 0, 0, 0};
        if (mrow + lrow < NN)
            a = *(const short8_t*)(aggb + (mrow + lrow) * H + kk * 32 + lk * 8);
        #pragma unroll
        for (int ct = 0; ct < 16; ++ct)
            acc[ct] = __builtin_amdgcn_mfma_f32_16x16x32_bf16(
                a, bfr1[(kk * 16 + ct) * 64 + l], acc[ct], 0, 0, 0);
    }
    #pragma unroll
    for (int ct = 0; ct < 16; ++ct) {
        const float b = b1[ct * 16 + lrow];
        #pragma unroll
        for (int r = 0; r < 4; ++r) {
            float v = acc[ct][r] + b;
            s_h[(lk * 4 + r) * SHP + ct * 16 + lrow] = f2bf(v > 0.f ? v : 0.f);
        }
    }
    __syncthreads();

    // ---- layer 2 ----
    f32x4 acc2[8];
    #pragma unroll
    for (int ct = 0; ct < 8; ++ct) acc2[ct] = (f32x4){0.f, 0.f, 0.f, 0.f};
    const short8_t* bfr2 = (const short8_t*)w2p;
    #pragma unroll
    for (int kk = 0; kk < 8; ++kk) {
        const short8_t a = *(const short8_t*)&s_h[lrow * SHP + kk * 32 + lk * 8];
        #pragma unroll
        for (int ct = 0; ct < 8; ++ct)
            acc2[ct] = __builtin_amdgcn_mfma_f32_16x16x32_bf16(
                a, bfr2[(kk * 8 + ct) * 64 + l], acc2[ct], 0, 0, 0);
    }
    __syncthreads();

    float* sc = (float*)s_h;
    #pragma unroll
    for (int ct = 0; ct < 8; ++ct) {
        const float b = b2[ct * 16 + lrow];
        #pragma unroll
        for (int r = 0; r < 4; ++r)
            sc[(lk * 4 + r) * 132 + ct * 16 + lrow] = acc2[ct][r] + b;
    }
    __syncthreads();

    #pragma unroll
    for (int it = 0; it < 8; ++it) {
        const int off = it * 64 + l;            // float4 units, 0..511
        const long long row = mrow + (off >> 5);
        if (row < NN) {
            const float4 v = *(const float4*)&sc[(off >> 5) * 132 + (off & 31) * 4];
            *(float4*)(out + row * H + (off & 31) * 4) = v;
        }
    }
}

// ---------------------------------------------------------------------------
// Fallback path (tiny workspace): atomic scatter + simple MLP (all fp32).
// ---------------------------------------------------------------------------
__global__ __launch_bounds__(256) void scatter_kernel(
    const float* __restrict__ node_feat,
    const float* __restrict__ edge_feat,
    const int*   __restrict__ edge_src,
    const int*   __restrict__ edge_dst,
    float*       __restrict__ agg)
{
    long long tid = (long long)blockIdx.x * blockDim.x + threadIdx.x;
    const long long total = (long long)NE * 32;
    if (tid >= total) return;
    int e = (int)(tid >> 5);
    int q = (int)((tid & 31) << 2);
    int s = edge_src[e];
    int d = edge_dst[e];
    const float4 nf = *(const float4*)(node_feat + (long long)s * H + q);
    const float4 ef = *(const float4*)(edge_feat + (long long)e * H + q);
    float* dst = agg + (long long)d * H + q;
    atomicAdd(dst + 0, nf.x + ef.x);
    atomicAdd(dst + 1, nf.y + ef.y);
    atomicAdd(dst + 2, nf.z + ef.z);
    atomicAdd(dst + 3, nf.w + ef.w);
}

__global__ __launch_bounds__(256) void mlp_simple_kernel(
    const float* __restrict__ agg,
    const float* __restrict__ w1, const float* __restrict__ b1,
    const float* __restrict__ w2, const float* __restrict__ b2,
    float*       __restrict__ out)
{
    constexpr int NPB = 16;
    __shared__ float s_in[NPB][H];
    __shared__ float s_h [NPB][H2];
    const int t = threadIdx.x;
    const long long base = (long long)blockIdx.x * NPB;
    {
        const float4* src = (const float4*)(agg + base * H);
        float4* dst = (float4*)(&s_in[0][0]);
        dst[t]       = src[t];
        dst[t + 256] = src[t + 256];
    }
    __syncthreads();
    float acc[NPB];
    {
        const float b = b1[t];
        #pragma unroll
        for (int n = 0; n < NPB; ++n) acc[n] = b;
    }
    #pragma unroll 4
    for (int k = 0; k < H; ++k) {
        const float w = w1[k * H2 + t];
        #pragma unroll
        for (int n = 0; n < NPB; ++n) acc[n] = fmaf(s_in[n][k], w, acc[n]);
    }
    #pragma unroll
    for (int n = 0; n < NPB; ++n) s_h[n][t] = fmaxf(acc[n], 0.0f);
    __syncthreads();
    const int j = t & (H - 1);
    const int g = t >> 7;
    float acc2[NPB / 2];
    {
        const float b = b2[j];
        #pragma unroll
        for (int n = 0; n < NPB / 2; ++n) acc2[n] = b;
    }
    #pragma unroll 4
    for (int k = 0; k < H2; ++k) {
        const float w = w2[k * H + j];
        #pragma unroll
        for (int n = 0; n < NPB / 2; ++n)
            acc2[n] = fmaf(s_h[g * (NPB / 2) + n][k], w, acc2[n]);
    }
    #pragma unroll
    for (int n = 0; n < NPB / 2; ++n)
        out[(base + g * (NPB / 2) + n) * H + j] = acc2[n];
}

__global__ __launch_bounds__(256) void zero_agg_kernel(float4* __restrict__ p, int n4)
{
    int i = blockIdx.x * blockDim.x + threadIdx.x;
    if (i < n4) p[i] = make_float4(0.f, 0.f, 0.f, 0.f);
}

// ---------------------------------------------------------------------------
extern "C" void kernel_launch(void* const* d_in, const int* in_sizes, int n_in,
                              void* d_out, int out_size, void* d_ws, size_t ws_size,
                              hipStream_t stream)
{
    const float* node_feat = (const float*)d_in[0];
    const float* edge_feat = (const float*)d_in[1];
    const int*   edge_src  = (const int*)  d_in[2];
    const int*   edge_dst  = (const int*)  d_in[3];
    const float* w1 = (const float*)d_in[4];
    const float* b1 = (const float*)d_in[5];
    const float* w2 = (const float*)d_in[6];
    const float* b2 = (const float*)d_in[7];
    float* out = (float*)d_out;

    // Workspace layout (256-B aligned regions)
    const size_t cursor_b = ((size_t)NN * 4 + 255) & ~(size_t)255;         // 200 KB
    const size_t w1p_b    = (size_t)32768 * 2;                             // 64 KB
    const size_t w2p_b    = (size_t)32768 * 2;                             // 64 KB
    const size_t bucket_b = (size_t)NN * CAP * 8;                          // 25.6 MB
    const size_t aggb_b   = ((size_t)NN * H * 2 + 255) & ~(size_t)255;     // 12.8 MB
    const size_t need     = cursor_b + w1p_b + w2p_b + bucket_b + aggb_b;  // ~38.7 MB

    if (ws_size >= need) {
        char* p = (char*)d_ws;
        int*   cursor = (int*)p;                 p += cursor_b;
        short* w1p    = (short*)p;               p += w1p_b;
        short* w2p    = (short*)p;               p += w2p_b;
        int2*  bucket = (int2*)p;                p += bucket_b;
        short* aggb   = (short*)p;

        pack_zero_kernel<<<128, 256, 0, stream>>>(w1, w2, w1p, w2p, cursor);
        const int eb = 256;
        const int eg = (NE / 2 + eb - 1) / eb;         // 1563 (2 edges/thread)
        place_kernel<<<eg, eb, 0, stream>>>(edge_dst, edge_src, cursor, bucket);
        gather_kernel<<<NN / 4, 256, 0, stream>>>(
            node_feat, edge_feat, bucket, cursor, aggb);
        const int mlp_grid = (NN + 63) / 64;           // 782
        mlp_kernel<<<mlp_grid, 256, 0, stream>>>(aggb, w1p, w2p, b1, b2, out);
    } else {
        // Fallback: atomic path + simple fp32 MLP
        const size_t agg_bytes = (size_t)NN * H * sizeof(float);
        float* agg = (ws_size >= agg_bytes) ? (float*)d_ws : out;
        {
            const int n4 = (int)(agg_bytes / 16);
            zero_agg_kernel<<<(n4 + 255) / 256, 256, 0, stream>>>((float4*)agg, n4);
        }
        const long long total = (long long)NE * 32;
        const int block = 256;
        const int grid  = (int)((total + block - 1) / block);
        scatter_kernel<<<grid, block, 0, stream>>>(
            node_feat, edge_feat, edge_src, edge_dst, agg);
        mlp_simple_kernel<<<NN / 16, 256, 0, stream>>>(agg, w1, b1, w2, b2, out);
    }
}